// Round 2
// baseline (3137.726 us; speedup 1.0000x reference)
//
#include <hip/hip_runtime.h>
#include <math.h>

#define S_LEN 2048
#define EMB_D 2048
#define N_HEADS 16
#define N_KV 8
#define HD 128
#define BSZ 2

// ---------------------------------------------------------------------------
// RoPE trig table: tab[s][j] = (cos(s*invf_j), sin(s*invf_j)), invf_j = 10000^(-j/64)
// ---------------------------------------------------------------------------
__global__ void trig_kernel(float2* __restrict__ tab) {
    const int s = blockIdx.x;
    const int j = threadIdx.x;           // 0..63
    const float inv = powf(10000.0f, -(float)j / 64.0f);
    const float ang = (float)s * inv;
    float sv, cv;
    sincosf(ang, &sv, &cv);
    tab[s * 64 + j] = make_float2(cv, sv);
}

// ---------------------------------------------------------------------------
// fp32 NT GEMM: C[m][n] = sum_k A[m][k] * B[n][k]
// 64x64 tile, BK=32, 256 threads, 4x4 per thread, LDS transposed with pad.
// M % 64 == 0, N % 64 == 0, K % 32 == 0 assumed.
// ---------------------------------------------------------------------------
__global__ __launch_bounds__(256) void sgemm_nt(const float* __restrict__ A,
                                                const float* __restrict__ Bm,
                                                float* __restrict__ C,
                                                int M, int N, int K) {
    __shared__ float As[32][68];   // [k][m], stride 68 floats = 272B (16B aligned)
    __shared__ float Bs[32][68];   // [k][n]

    const int tid = threadIdx.x;
    const int bm = blockIdx.x * 64;
    const int bn = blockIdx.y * 64;
    const int ty = tid >> 4;       // 0..15 -> rows ty*4..+3
    const int tx = tid & 15;       // 0..15 -> cols tx*4..+3

    const int lr = tid >> 2;       // 0..63 tile row
    const int lc = tid & 3;        // 0..3  k-group
    const float* Aptr = A + (size_t)(bm + lr) * K + lc * 4;
    const float* Bptr = Bm + (size_t)(bn + lr) * K + lc * 4;

    float acc[4][4] = {};

    for (int k0 = 0; k0 < K; k0 += 32) {
        const float4 a0 = *(const float4*)(Aptr + k0);
        const float4 a1 = *(const float4*)(Aptr + k0 + 16);
        const float4 b0 = *(const float4*)(Bptr + k0);
        const float4 b1 = *(const float4*)(Bptr + k0 + 16);
        __syncthreads();   // previous iteration's readers done
        {
            const int kbase = lc * 4;
            As[kbase + 0][lr] = a0.x;  As[kbase + 1][lr] = a0.y;
            As[kbase + 2][lr] = a0.z;  As[kbase + 3][lr] = a0.w;
            As[kbase + 16][lr] = a1.x; As[kbase + 17][lr] = a1.y;
            As[kbase + 18][lr] = a1.z; As[kbase + 19][lr] = a1.w;
            Bs[kbase + 0][lr] = b0.x;  Bs[kbase + 1][lr] = b0.y;
            Bs[kbase + 2][lr] = b0.z;  Bs[kbase + 3][lr] = b0.w;
            Bs[kbase + 16][lr] = b1.x; Bs[kbase + 17][lr] = b1.y;
            Bs[kbase + 18][lr] = b1.z; Bs[kbase + 19][lr] = b1.w;
        }
        __syncthreads();
        #pragma unroll
        for (int kk = 0; kk < 32; ++kk) {
            const float4 av = *(const float4*)&As[kk][ty * 4];
            const float4 bv = *(const float4*)&Bs[kk][tx * 4];
            const float a_[4] = {av.x, av.y, av.z, av.w};
            const float b_[4] = {bv.x, bv.y, bv.z, bv.w};
            #pragma unroll
            for (int i = 0; i < 4; ++i)
                #pragma unroll
                for (int j = 0; j < 4; ++j)
                    acc[i][j] += a_[i] * b_[j];
        }
    }

    #pragma unroll
    for (int i = 0; i < 4; ++i) {
        float4 o = make_float4(acc[i][0], acc[i][1], acc[i][2], acc[i][3]);
        *(float4*)(C + (size_t)(bm + ty * 4 + i) * N + bn + tx * 4) = o;
    }
}

// ---------------------------------------------------------------------------
// RoPE + head-split transpose.
// src: (B, S, H*128) with column e = d*H + h   (heads fastest)
// dst: (B, H, S, 128)
// rope: 1 -> rotate-half RoPE on d axis; 0 -> plain transpose (V)
// ---------------------------------------------------------------------------
__global__ __launch_bounds__(128) void rope_transpose(const float* __restrict__ src,
                                                      float* __restrict__ dst,
                                                      const float2* __restrict__ tab,
                                                      int H, int rope) {
    const int s = blockIdx.x;
    const int b = blockIdx.y;
    const int tid = threadIdx.x;     // 0..127
    const int len = H * HD;

    __shared__ float row[EMB_D];

    const float* sp = src + ((size_t)b * S_LEN + s) * len;
    for (int i = tid * 4; i < len; i += 128 * 4)
        *(float4*)&row[i] = *(const float4*)(sp + i);
    __syncthreads();

    const int d = tid;               // 0..127
    const float2 cs = tab[s * 64 + (d & 63)];

    for (int h = 0; h < H; ++h) {
        const float xv = row[d * H + h];
        float out;
        if (!rope) {
            out = xv;
        } else if (d < 64) {
            out = xv * cs.x - row[(d + 64) * H + h] * cs.y;
        } else {
            out = xv * cs.x + row[(d - 64) * H + h] * cs.y;
        }
        dst[(((size_t)b * H + h) * S_LEN + s) * HD + d] = out;
    }
}

// ---------------------------------------------------------------------------
// fp32 flash attention (non-causal, full softmax over t).
// One block = (b, h, 32 q-rows). 256 threads.
// Qh: (B, 16, S, 128)  Kh/Vh: (B, 8, S, 128)  Ctx: (B, S, 2048) col = h*128+d
// ---------------------------------------------------------------------------
__global__ __launch_bounds__(256) void attn_kernel(const float* __restrict__ Qh,
                                                   const float* __restrict__ Kh,
                                                   const float* __restrict__ Vh,
                                                   float* __restrict__ Ctx) {
    const int qb = blockIdx.x;      // 0..63
    const int h  = blockIdx.y;      // 0..15
    const int b  = blockIdx.z;
    const int kv = h >> 1;
    const int tid = threadIdx.x;

    __shared__ float Qs[32][132];
    __shared__ float Ks[32][132];
    __shared__ float Vs[32][132];
    __shared__ float Ss[32][36];
    __shared__ float mrow[32], lrow[32], resc[32];

    const float scale = 0.022097086912079608f;   // 1/sqrt(2048)

    const float* Qbase = Qh + (((size_t)b * N_HEADS + h) * S_LEN + qb * 32) * HD;
    const float* Kbase = Kh + ((size_t)b * N_KV + kv) * S_LEN * HD;
    const float* Vbase = Vh + ((size_t)b * N_KV + kv) * S_LEN * HD;

    // load + scale Q tile (32x128)
    {
        const int r = tid >> 3;
        const int c = (tid & 7) * 16;
        const float* qp = Qbase + r * HD + c;
        #pragma unroll
        for (int u = 0; u < 4; ++u) {
            float4 v = *(const float4*)(qp + u * 4);
            v.x *= scale; v.y *= scale; v.z *= scale; v.w *= scale;
            *(float4*)&Qs[r][c + u * 4] = v;
        }
    }
    if (tid < 32) { mrow[tid] = -1e30f; lrow[tid] = 0.0f; }

    float O[2][8] = {};
    const int ty = tid >> 4;    // QK: score rows ty*2..+1
    const int tx = tid & 15;    // QK: score cols tx*2..+1
    const int sr = tid >> 3;    // softmax row
    const int sj = tid & 7;     // softmax col group (4 cols)
    const int pr = tid >> 4;    // PV: rows pr*2..+1
    const int pc = tid & 15;    // PV: cols pc*8..+7

    for (int t0 = 0; t0 < S_LEN; t0 += 32) {
        __syncthreads();   // prev PV readers of Vs/Ss done
        // stage K,V tile (32x128 each)
        {
            const int r = tid >> 3;
            const int c = (tid & 7) * 16;
            const float* kp = Kbase + (size_t)(t0 + r) * HD + c;
            const float* vp = Vbase + (size_t)(t0 + r) * HD + c;
            #pragma unroll
            for (int u = 0; u < 4; ++u) {
                *(float4*)&Ks[r][c + u * 4] = *(const float4*)(kp + u * 4);
                *(float4*)&Vs[r][c + u * 4] = *(const float4*)(vp + u * 4);
            }
        }
        __syncthreads();
        // QK^T -> Ss (32x32)
        {
            float a00 = 0.f, a01 = 0.f, a10 = 0.f, a11 = 0.f;
            #pragma unroll
            for (int d4 = 0; d4 < 32; ++d4) {
                const float4 q0 = *(const float4*)&Qs[ty * 2 + 0][d4 * 4];
                const float4 q1 = *(const float4*)&Qs[ty * 2 + 1][d4 * 4];
                const float4 k0 = *(const float4*)&Ks[tx * 2 + 0][d4 * 4];
                const float4 k1 = *(const float4*)&Ks[tx * 2 + 1][d4 * 4];
                a00 += q0.x * k0.x + q0.y * k0.y + q0.z * k0.z + q0.w * k0.w;
                a01 += q0.x * k1.x + q0.y * k1.y + q0.z * k1.z + q0.w * k1.w;
                a10 += q1.x * k0.x + q1.y * k0.y + q1.z * k0.z + q1.w * k0.w;
                a11 += q1.x * k1.x + q1.y * k1.y + q1.z * k1.z + q1.w * k1.w;
            }
            Ss[ty * 2 + 0][tx * 2 + 0] = a00;
            Ss[ty * 2 + 0][tx * 2 + 1] = a01;
            Ss[ty * 2 + 1][tx * 2 + 0] = a10;
            Ss[ty * 2 + 1][tx * 2 + 1] = a11;
        }
        __syncthreads();
        // online softmax over this 32-col tile
        {
            float4 sv = *(const float4*)&Ss[sr][sj * 4];
            float mx = fmaxf(fmaxf(sv.x, sv.y), fmaxf(sv.z, sv.w));
            mx = fmaxf(mx, __shfl_xor(mx, 1));
            mx = fmaxf(mx, __shfl_xor(mx, 2));
            mx = fmaxf(mx, __shfl_xor(mx, 4));
            const float mold = mrow[sr];
            const float mnew = fmaxf(mold, mx);
            const float p0 = __expf(sv.x - mnew);
            const float p1 = __expf(sv.y - mnew);
            const float p2 = __expf(sv.z - mnew);
            const float p3 = __expf(sv.w - mnew);
            float sum = p0 + p1 + p2 + p3;
            sum += __shfl_xor(sum, 1);
            sum += __shfl_xor(sum, 2);
            sum += __shfl_xor(sum, 4);
            *(float4*)&Ss[sr][sj * 4] = make_float4(p0, p1, p2, p3);
            if (sj == 0) {
                const float rs = __expf(mold - mnew);
                lrow[sr] = lrow[sr] * rs + sum;
                resc[sr] = rs;
                mrow[sr] = mnew;
            }
        }
        __syncthreads();
        // PV accumulate: O[2 rows][8 cols]
        {
            const float r0 = resc[pr * 2 + 0];
            const float r1 = resc[pr * 2 + 1];
            #pragma unroll
            for (int c = 0; c < 8; ++c) { O[0][c] *= r0; O[1][c] *= r1; }
            #pragma unroll
            for (int tt = 0; tt < 32; ++tt) {
                const float p0 = Ss[pr * 2 + 0][tt];
                const float p1 = Ss[pr * 2 + 1][tt];
                const float4 v0 = *(const float4*)&Vs[tt][pc * 8];
                const float4 v1 = *(const float4*)&Vs[tt][pc * 8 + 4];
                O[0][0] += p0 * v0.x; O[0][1] += p0 * v0.y;
                O[0][2] += p0 * v0.z; O[0][3] += p0 * v0.w;
                O[0][4] += p0 * v1.x; O[0][5] += p0 * v1.y;
                O[0][6] += p0 * v1.z; O[0][7] += p0 * v1.w;
                O[1][0] += p1 * v0.x; O[1][1] += p1 * v0.y;
                O[1][2] += p1 * v0.z; O[1][3] += p1 * v0.w;
                O[1][4] += p1 * v1.x; O[1][5] += p1 * v1.y;
                O[1][6] += p1 * v1.z; O[1][7] += p1 * v1.w;
            }
        }
    }

    // epilogue: normalize and write Ctx (B, S, 2048), col = h*128 + d
    {
        const float inv0 = 1.0f / lrow[pr * 2 + 0];
        const float inv1 = 1.0f / lrow[pr * 2 + 1];
        const size_t base = ((size_t)b * S_LEN + qb * 32 + pr * 2) * EMB_D + h * HD + pc * 8;
        *(float4*)&Ctx[base]             = make_float4(O[0][0] * inv0, O[0][1] * inv0, O[0][2] * inv0, O[0][3] * inv0);
        *(float4*)&Ctx[base + 4]         = make_float4(O[0][4] * inv0, O[0][5] * inv0, O[0][6] * inv0, O[0][7] * inv0);
        *(float4*)&Ctx[base + EMB_D]     = make_float4(O[1][0] * inv1, O[1][1] * inv1, O[1][2] * inv1, O[1][3] * inv1);
        *(float4*)&Ctx[base + EMB_D + 4] = make_float4(O[1][4] * inv1, O[1][5] * inv1, O[1][6] * inv1, O[1][7] * inv1);
    }
}

// ---------------------------------------------------------------------------
extern "C" void kernel_launch(void* const* d_in, const int* in_sizes, int n_in,
                              void* d_out, int out_size, void* d_ws, size_t ws_size,
                              hipStream_t stream) {
    const float* x  = (const float*)d_in[0];   // (2, 2048, 2048)
    const float* Wq = (const float*)d_in[1];   // (2048, 2048)
    const float* Wk = (const float*)d_in[2];   // (1024, 2048)
    const float* Wv = (const float*)d_in[3];   // (1024, 2048)
    const float* Wo = (const float*)d_in[4];   // (2048, 2048)
    float* out = (float*)d_out;                // (2, 2048, 2048)
    float* ws  = (float*)d_ws;

    // workspace layout (floats)
    float2* tab  = (float2*)ws;                         //   262,144 f
    float* qproj = ws + 262144;                         // 8,388,608 f (reused as Ctx)
    float* kproj = qproj + 8388608;                     // 4,194,304 f
    float* vproj = kproj + 4194304;                     // 4,194,304 f
    float* Qh    = vproj + 4194304;                     // 8,388,608 f
    float* Kh    = Qh + 8388608;                        // 4,194,304 f
    float* Vh    = Kh + 4194304;                        // 4,194,304 f
    float* Ctx   = qproj;                               // alias: qproj dead after rope

    const int M = BSZ * S_LEN;   // 4096

    trig_kernel<<<dim3(S_LEN), dim3(64), 0, stream>>>(tab);

    sgemm_nt<<<dim3(M / 64, EMB_D / 64), 256, 0, stream>>>(x, Wq, qproj, M, EMB_D, EMB_D);
    sgemm_nt<<<dim3(M / 64, 1024 / 64), 256, 0, stream>>>(x, Wk, kproj, M, 1024, EMB_D);
    sgemm_nt<<<dim3(M / 64, 1024 / 64), 256, 0, stream>>>(x, Wv, vproj, M, 1024, EMB_D);

    rope_transpose<<<dim3(S_LEN, BSZ), 128, 0, stream>>>(qproj, Qh, tab, N_HEADS, 1);
    rope_transpose<<<dim3(S_LEN, BSZ), 128, 0, stream>>>(kproj, Kh, tab, N_KV, 1);
    rope_transpose<<<dim3(S_LEN, BSZ), 128, 0, stream>>>(vproj, Vh, tab, N_KV, 0);

    attn_kernel<<<dim3(S_LEN / 32, N_HEADS, BSZ), 256, 0, stream>>>(Qh, Kh, Vh, Ctx);

    sgemm_nt<<<dim3(M / 64, EMB_D / 64), 256, 0, stream>>>(Ctx, Wo, out, M, EMB_D, EMB_D);
}

// Round 7
// 1686.309 us; speedup vs baseline: 1.8607x; 1.8607x over previous
//
#include <hip/hip_runtime.h>
#include <math.h>

#define S_LEN 2048
#define EMB_D 2048
#define N_HEADS 16
#define N_KV 8
#define HD 128
#define BSZ 2
#define V_W 1024   // V/K projection row width (EMB/G)

typedef unsigned short u16;
typedef unsigned int u32;
typedef __attribute__((ext_vector_type(8))) short bf16x8s;
typedef __attribute__((ext_vector_type(4))) float f32x4;

static __device__ __forceinline__ u16 f2bf(float x) {
    union { float f; u32 u; } c; c.f = x;
    u32 r = c.u + 0x7fff + ((c.u >> 16) & 1);
    return (u16)(r >> 16);
}

// ---------------------------------------------------------------------------
// RoPE trig table: tab[s][j] = (cos, sin)(s * 10000^(-j/64))
// ---------------------------------------------------------------------------
__global__ void trig_kernel(float2* __restrict__ tab) {
    const int s = blockIdx.x;
    const int j = threadIdx.x;           // 0..63
    const float inv = powf(10000.0f, -(float)j / 64.0f);
    float sv, cv;
    sincosf((float)s * inv, &sv, &cv);
    tab[s * 64 + j] = make_float2(cv, sv);
}

// ---------------------------------------------------------------------------
// fp32 NT GEMM (verified round 2): C[m][n] = sum_k A[m][k]*B[n][k]
// ---------------------------------------------------------------------------
__global__ __launch_bounds__(256) void sgemm_nt(const float* __restrict__ A,
                                                const float* __restrict__ Bm,
                                                float* __restrict__ C,
                                                int M, int N, int K) {
    __shared__ float As[32][68];
    __shared__ float Bs[32][68];

    const int tid = threadIdx.x;
    const int bm = blockIdx.x * 64;
    const int bn = blockIdx.y * 64;
    const int ty = tid >> 4;
    const int tx = tid & 15;

    const int lr = tid >> 2;
    const int lc = tid & 3;
    const float* Aptr = A + (size_t)(bm + lr) * K + lc * 4;
    const float* Bptr = Bm + (size_t)(bn + lr) * K + lc * 4;

    float acc[4][4] = {};

    for (int k0 = 0; k0 < K; k0 += 32) {
        const float4 a0 = *(const float4*)(Aptr + k0);
        const float4 a1 = *(const float4*)(Aptr + k0 + 16);
        const float4 b0 = *(const float4*)(Bptr + k0);
        const float4 b1 = *(const float4*)(Bptr + k0 + 16);
        __syncthreads();
        {
            const int kb = lc * 4;
            As[kb + 0][lr] = a0.x;  As[kb + 1][lr] = a0.y;
            As[kb + 2][lr] = a0.z;  As[kb + 3][lr] = a0.w;
            As[kb + 16][lr] = a1.x; As[kb + 17][lr] = a1.y;
            As[kb + 18][lr] = a1.z; As[kb + 19][lr] = a1.w;
            Bs[kb + 0][lr] = b0.x;  Bs[kb + 1][lr] = b0.y;
            Bs[kb + 2][lr] = b0.z;  Bs[kb + 3][lr] = b0.w;
            Bs[kb + 16][lr] = b1.x; Bs[kb + 17][lr] = b1.y;
            Bs[kb + 18][lr] = b1.z; Bs[kb + 19][lr] = b1.w;
        }
        __syncthreads();
        #pragma unroll
        for (int kk = 0; kk < 32; ++kk) {
            const float4 av = *(const float4*)&As[kk][ty * 4];
            const float4 bv = *(const float4*)&Bs[kk][tx * 4];
            const float a_[4] = {av.x, av.y, av.z, av.w};
            const float b_[4] = {bv.x, bv.y, bv.z, bv.w};
            #pragma unroll
            for (int i = 0; i < 4; ++i)
                #pragma unroll
                for (int j = 0; j < 4; ++j)
                    acc[i][j] += a_[i] * b_[j];
        }
    }

    #pragma unroll
    for (int i = 0; i < 4; ++i) {
        float4 o = make_float4(acc[i][0], acc[i][1], acc[i][2], acc[i][3]);
        *(float4*)(C + (size_t)(bm + ty * 4 + i) * N + bn + tx * 4) = o;
    }
}

// ---------------------------------------------------------------------------
// RoPE + head-split transpose, bf16 output.
// src: (B,S,H*128) fp32, col e = d*H + h  ->  dst: (B,H,S,128) bf16
// ---------------------------------------------------------------------------
__global__ __launch_bounds__(128) void rope_bf16(const float* __restrict__ src,
                                                 u16* __restrict__ dst,
                                                 const float2* __restrict__ tab,
                                                 int H) {
    const int s = blockIdx.x;
    const int b = blockIdx.y;
    const int tid = threadIdx.x;     // 0..127
    const int len = H * HD;

    __shared__ float row[EMB_D];

    const float* sp = src + ((size_t)b * S_LEN + s) * len;
    for (int i = tid * 4; i < len; i += 128 * 4)
        *(float4*)&row[i] = *(const float4*)(sp + i);
    __syncthreads();

    const int d = tid;
    const float2 cs = tab[s * 64 + (d & 63)];

    for (int h = 0; h < H; ++h) {
        const float xv = row[d * H + h];
        float out;
        if (d < 64)
            out = xv * cs.x - row[(d + 64) * H + h] * cs.y;
        else
            out = xv * cs.x + row[(d - 64) * H + h] * cs.y;
        dst[(((size_t)b * H + h) * S_LEN + s) * HD + d] = f2bf(out);
    }
}

// ---------------------------------------------------------------------------
// V transpose: vproj (B,S,1024) fp32 (e = d*8+kv) -> Vtg (B,8,128,S) bf16
// FIX(r7): row stride is V_W=1024 (W_V is 1024x2048) — rounds 4/5 used 2048,
// reading V rows from wrong positions (the ~0.11 absmax signature).
// ---------------------------------------------------------------------------
__global__ __launch_bounds__(256) void v_transpose(const float* __restrict__ vproj,
                                                   u16* __restrict__ Vtg) {
    const int s0 = blockIdx.x * 64;
    const int kv = blockIdx.y;
    const int b  = blockIdx.z;
    const int tid = threadIdx.x;

    __shared__ u16 tile[128][72];

    {
        const int s = tid >> 2, dg = tid & 3;
        const float* src = vproj + ((size_t)(b * S_LEN) + s0 + s) * V_W + kv;
        #pragma unroll
        for (int dd = 0; dd < 32; ++dd) {
            const int d = dg * 32 + dd;
            tile[d][s] = f2bf(src[(size_t)d * 8]);
        }
    }
    __syncthreads();
    {
        const int d = tid >> 1, hf = tid & 1;
        u16* dst = Vtg + (((size_t)(b * N_KV + kv)) * HD + d) * S_LEN + s0 + hf * 32;
        #pragma unroll
        for (int u = 0; u < 4; ++u) {
            const u16* t = &tile[d][hf * 32 + u * 8];
            uint4 o;
            o.x = (u32)t[0] | ((u32)t[1] << 16);
            o.y = (u32)t[2] | ((u32)t[3] << 16);
            o.z = (u32)t[4] | ((u32)t[5] << 16);
            o.w = (u32)t[6] | ((u32)t[7] << 16);
            *(uint4*)(dst + u * 8) = o;
        }
    }
}

// ---------------------------------------------------------------------------
// MFMA flash attention on the end-to-end-verified 16x16x32 conventions ONLY:
//   A-frag: lane holds A[row=lane&15][k = 8*(lane>>4)+j] (8 contiguous bf16)
//   B-frag: lane holds B[col=lane&15][k = 8*(lane>>4)+j] (operand stored NT)
//   D:      col = lane&15, row = 4*(lane>>4) + reg
// Block = 64 q-rows, 4 waves (16 q each). KV tile = 32.
// QK^T: D=S[q16][key16] x2 key-halves, A=Q regs, B=Ks rows. S -> LDS (f32).
// Softmax: round-2-verified pattern, 4 threads/row, always-rescale.
// PV: O^T[d][q], A=Vt rows, B=Pl rows ([q][t] bf16).  All softmax/PV deps
// are intra-wave -> only 2 barriers/tile (staging).
// ---------------------------------------------------------------------------
__global__ __launch_bounds__(256) void attn_mfma16(const u16* __restrict__ Qh,
                                                   const u16* __restrict__ Kh,
                                                   const u16* __restrict__ Vtg,
                                                   float* __restrict__ Ctx) {
    __shared__ u16 Ks[32][136];     // [key][d], 272B rows
    __shared__ u16 Vt[128][40];     // [d][t], 80B rows
    __shared__ float Ss[64][36];    // [q][t] raw scores, 144B rows
    __shared__ u16 Pl[64][40];      // [q][t] bf16 probs, 80B rows
    __shared__ float mrow[64], lrow[64], resc[64];

    const int orig = blockIdx.x;                     // 1024 blocks
    const int wg = (orig & 7) * 128 + (orig >> 3);   // XCD-bijective swizzle
    const int qb = wg & 31;
    const int h  = (wg >> 5) & 15;
    const int b  = wg >> 9;
    const int kv = h >> 1;
    const int tid = threadIdx.x;
    const int w    = tid >> 6;      // wave 0..3
    const int lane = tid & 63;
    const int r16  = lane & 15;
    const int g4   = lane >> 4;     // 0..3

    const float scale = 0.022097086912079608f;   // 1/sqrt(2048)

    const u16* Kbase = Kh + ((size_t)(b * N_KV + kv)) * S_LEN * HD;
    const u16* Vbase = Vtg + ((size_t)(b * N_KV + kv)) * HD * S_LEN;

    // Q fragments in regs: q = qb*64 + w*16 + r16; chunk c: d = 32c + 8*g4 + j
    bf16x8s qf[4];
    {
        const u16* qrow = Qh + (((size_t)(b * N_HEADS + h)) * S_LEN + qb * 64 + w * 16 + r16) * HD + 8 * g4;
        #pragma unroll
        for (int c = 0; c < 4; ++c)
            qf[c] = *(const bf16x8s*)(qrow + c * 32);
    }

    f32x4 acc[8];
    #pragma unroll
    for (int dt = 0; dt < 8; ++dt)
        #pragma unroll
        for (int r = 0; r < 4; ++r) acc[dt][r] = 0.0f;

    if (tid < 64) { mrow[tid] = -1e30f; lrow[tid] = 0.0f; }

    // staging assignment (as verified structure)
    const int krow = tid >> 3, kslot = tid & 7;   // K tile: 32 rows x 16B slots
    const int vrow = tid >> 1, vhalf = tid & 1;   // Vt tile: 128 rows x halves

    uint4 kp0, kp1, vp0, vp1;
    kp0 = kp1 = vp0 = vp1 = make_uint4(0, 0, 0, 0);

    #define LOADT(t0) do {                                                  \
        const u16* kp = Kbase + (size_t)((t0) + krow) * HD + kslot * 8;     \
        kp0 = *(const uint4*)kp;                                            \
        kp1 = *(const uint4*)(kp + 64);                                     \
        const u16* vp = Vbase + (size_t)vrow * S_LEN + (t0) + vhalf * 16;   \
        vp0 = *(const uint4*)vp;                                            \
        vp1 = *(const uint4*)(vp + 8);                                      \
    } while (0)

    LOADT(0);

    for (int t = 0; t < S_LEN / 32; ++t) {
        __syncthreads();   // all waves done reading Ks/Vt of prev tile (+init visible)
        *(uint4*)&Ks[krow][kslot * 8]      = kp0;
        *(uint4*)&Ks[krow][kslot * 8 + 64] = kp1;
        *(uint4*)&Vt[vrow][vhalf * 16]     = vp0;
        *(uint4*)&Vt[vrow][vhalf * 16 + 8] = vp1;
        __syncthreads();   // tile staged
        if (t + 1 < S_LEN / 32) LOADT((t + 1) * 32);

        // ---- QK^T: S[q][key], two key-halves ----
        f32x4 s0, s1;
        #pragma unroll
        for (int r = 0; r < 4; ++r) { s0[r] = 0.0f; s1[r] = 0.0f; }
        #pragma unroll
        for (int c = 0; c < 4; ++c) {
            bf16x8s kb0 = *(const bf16x8s*)&Ks[r16][c * 32 + 8 * g4];
            bf16x8s kb1 = *(const bf16x8s*)&Ks[16 + r16][c * 32 + 8 * g4];
            s0 = __builtin_amdgcn_mfma_f32_16x16x32_bf16(qf[c], kb0, s0, 0, 0, 0);
            s1 = __builtin_amdgcn_mfma_f32_16x16x32_bf16(qf[c], kb1, s1, 0, 0, 0);
        }
        // D layout (verified): col = r16 (key), row = 4*g4 + reg (q-within-band)
        #pragma unroll
        for (int r = 0; r < 4; ++r) {
            Ss[w * 16 + 4 * g4 + r][r16]      = s0[r];
            Ss[w * 16 + 4 * g4 + r][16 + r16] = s1[r];
        }
        // intra-wave: wave w wrote rows [16w,16w+16) and reads them below

        // ---- softmax (round-2 pattern): 4 threads per row ----
        const int row = tid >> 2;      // 0..63, wave-local rows
        const int cg  = tid & 3;       // 8 cols each
        const float4 va = *(const float4*)&Ss[row][cg * 8];
        const float4 vb = *(const float4*)&Ss[row][cg * 8 + 4];
        float mx = fmaxf(fmaxf(fmaxf(va.x, va.y), fmaxf(va.z, va.w)),
                         fmaxf(fmaxf(vb.x, vb.y), fmaxf(vb.z, vb.w)));
        mx = fmaxf(mx, __shfl_xor(mx, 1));
        mx = fmaxf(mx, __shfl_xor(mx, 2));
        const float mold = mrow[row];
        const float mnew = fmaxf(mold, mx * scale);
        const float rs = __expf(mold - mnew);
        const float p0 = __expf(fmaf(va.x, scale, -mnew));
        const float p1 = __expf(fmaf(va.y, scale, -mnew));
        const float p2 = __expf(fmaf(va.z, scale, -mnew));
        const float p3 = __expf(fmaf(va.w, scale, -mnew));
        const float p4 = __expf(fmaf(vb.x, scale, -mnew));
        const float p5 = __expf(fmaf(vb.y, scale, -mnew));
        const float p6 = __expf(fmaf(vb.z, scale, -mnew));
        const float p7 = __expf(fmaf(vb.w, scale, -mnew));
        float sum = ((p0 + p1) + (p2 + p3)) + ((p4 + p5) + (p6 + p7));
        sum += __shfl_xor(sum, 1);
        sum += __shfl_xor(sum, 2);
        if (cg == 0) {
            lrow[row] = lrow[row] * rs + sum;
            mrow[row] = mnew;
            resc[row] = rs;
        }
        {
            const u32 w0 = (u32)f2bf(p0) | ((u32)f2bf(p1) << 16);
            const u32 w1 = (u32)f2bf(p2) | ((u32)f2bf(p3) << 16);
            const u32 w2 = (u32)f2bf(p4) | ((u32)f2bf(p5) << 16);
            const u32 w3 = (u32)f2bf(p6) | ((u32)f2bf(p7) << 16);
            *(uint2*)&Pl[row][cg * 8]     = make_uint2(w0, w1);
            *(uint2*)&Pl[row][cg * 8 + 4] = make_uint2(w2, w3);
        }
        // intra-wave: wave w's PV reads rows [16w,16w+16) of Pl/resc (own rows)

        // ---- PV: O^T[d][q] += Vt * P^T ----
        const float f = resc[w * 16 + r16];
        #pragma unroll
        for (int dt = 0; dt < 8; ++dt)
            #pragma unroll
            for (int r = 0; r < 4; ++r) acc[dt][r] *= f;
        const bf16x8s pb = *(const bf16x8s*)&Pl[w * 16 + r16][8 * g4];
        #pragma unroll
        for (int dt = 0; dt < 8; ++dt) {
            bf16x8s vv = *(const bf16x8s*)&Vt[16 * dt + r16][8 * g4];
            acc[dt] = __builtin_amdgcn_mfma_f32_16x16x32_bf16(vv, pb, acc[dt], 0, 0, 0);
        }
    }

    // ---- epilogue: normalize, write Ctx (B,S,2048), col = h*128 + d ----
    // lane's q = w*16 + r16 (D col); rows d = 16*dt + 4*g4 + reg
    const float invl = 1.0f / lrow[w * 16 + r16];
    const size_t rowb = ((size_t)(b * S_LEN + qb * 64 + w * 16 + r16)) * EMB_D + h * HD;
    #pragma unroll
    for (int dt = 0; dt < 8; ++dt) {
        const int d = 16 * dt + 4 * g4;
        float4 o = make_float4(acc[dt][0] * invl, acc[dt][1] * invl,
                               acc[dt][2] * invl, acc[dt][3] * invl);
        *(float4*)&Ctx[rowb + d] = o;
    }
    #undef LOADT
}

// ---------------------------------------------------------------------------
extern "C" void kernel_launch(void* const* d_in, const int* in_sizes, int n_in,
                              void* d_out, int out_size, void* d_ws, size_t ws_size,
                              hipStream_t stream) {
    const float* x  = (const float*)d_in[0];   // (2,2048,2048)
    const float* Wq = (const float*)d_in[1];   // (2048,2048)
    const float* Wk = (const float*)d_in[2];   // (1024,2048)
    const float* Wv = (const float*)d_in[3];   // (1024,2048)
    const float* Wo = (const float*)d_in[4];   // (2048,2048)
    float* out = (float*)d_out;
    float* ws  = (float*)d_ws;

    // workspace layout (float offsets)
    float2* tab  = (float2*)ws;                    //   262,144 f
    float* qproj = ws + 262144;                    // 8,388,608 f (reused as Ctx)
    float* kproj = qproj + 8388608;                // 4,194,304 f
    float* vproj = kproj + 4194304;                // 4,194,304 f
    u16* Qh  = (u16*)(ws + 17039360);              // 8,388,608 u16
    u16* Kh  = (u16*)(ws + 21233664);              // 4,194,304 u16
    u16* Vtg = (u16*)(ws + 23330816);              // 4,194,304 u16
    float* Ctx = qproj;

    const int M = BSZ * S_LEN;   // 4096

    trig_kernel<<<dim3(S_LEN), dim3(64), 0, stream>>>(tab);

    sgemm_nt<<<dim3(M / 64, EMB_D / 64), 256, 0, stream>>>(x, Wq, qproj, M, EMB_D, EMB_D);
    sgemm_nt<<<dim3(M / 64, 1024 / 64), 256, 0, stream>>>(x, Wk, kproj, M, 1024, EMB_D);
    sgemm_nt<<<dim3(M / 64, 1024 / 64), 256, 0, stream>>>(x, Wv, vproj, M, 1024, EMB_D);

    rope_bf16<<<dim3(S_LEN, BSZ), 128, 0, stream>>>(qproj, Qh, tab, N_HEADS);
    rope_bf16<<<dim3(S_LEN, BSZ), 128, 0, stream>>>(kproj, Kh, tab, N_KV);
    v_transpose<<<dim3(S_LEN / 64, N_KV, BSZ), 256, 0, stream>>>(vproj, Vtg);

    attn_mfma16<<<dim3(1024), 256, 0, stream>>>(Qh, Kh, Vtg, Ctx);

    sgemm_nt<<<dim3(M / 64, EMB_D / 64), 256, 0, stream>>>(Ctx, Wo, out, M, EMB_D, EMB_D);
}

// Round 9
// 763.722 us; speedup vs baseline: 4.1085x; 2.2080x over previous
//
#include <hip/hip_runtime.h>
#include <math.h>

#define S_LEN 2048
#define EMB_D 2048
#define N_HEADS 16
#define N_KV 8
#define HD 128
#define BSZ 2
#define V_W 1024   // V/K projection row width (EMB/G)

typedef unsigned short u16;
typedef unsigned int u32;
typedef __attribute__((ext_vector_type(8))) short bf16x8s;
typedef __attribute__((ext_vector_type(4))) float f32x4;

static __device__ __forceinline__ u16 f2bf(float x) {
    union { float f; u32 u; } c; c.f = x;
    u32 r = c.u + 0x7fff + ((c.u >> 16) & 1);
    return (u16)(r >> 16);
}

// hi = truncated bf16 (top 16 bits); lo = rne-bf16(v - hi). hi|lo ~= 16-bit mantissa.
static __device__ __forceinline__ void split2(float x, float y, u32& hw, u32& lw) {
    u32 ux = __float_as_uint(x), uy = __float_as_uint(y);
    u32 hx = ux & 0xFFFF0000u,   hy = uy & 0xFFFF0000u;
    hw = (hx >> 16) | hy;
    u16 lx = f2bf(x - __uint_as_float(hx));
    u16 ly = f2bf(y - __uint_as_float(hy));
    lw = (u32)lx | ((u32)ly << 16);
}

// ---------------------------------------------------------------------------
// RoPE trig table: tab[s][j] = (cos, sin)(s * 10000^(-j/64))
// ---------------------------------------------------------------------------
__global__ void trig_kernel(float2* __restrict__ tab) {
    const int s = blockIdx.x;
    const int j = threadIdx.x;           // 0..63
    const float inv = powf(10000.0f, -(float)j / 64.0f);
    float sv, cv;
    sincosf((float)s * inv, &sv, &cv);
    tab[s * 64 + j] = make_float2(cv, sv);
}

// ---------------------------------------------------------------------------
// Weight split: src (n fp32) -> hi, lo bf16 arrays (n each). n % 2048 == 0.
// ---------------------------------------------------------------------------
__global__ __launch_bounds__(256) void split_bf16(const float* __restrict__ src,
                                                  u16* __restrict__ hi,
                                                  u16* __restrict__ lo, int n8) {
    const int i = blockIdx.x * 256 + threadIdx.x;
    if (i >= n8) return;
    const float4 v0 = ((const float4*)src)[i * 2];
    const float4 v1 = ((const float4*)src)[i * 2 + 1];
    uint4 h, l;
    split2(v0.x, v0.y, h.x, l.x);
    split2(v0.z, v0.w, h.y, l.y);
    split2(v1.x, v1.y, h.z, l.z);
    split2(v1.z, v1.w, h.w, l.w);
    ((uint4*)hi)[i] = h;
    ((uint4*)lo)[i] = l;
}

// ---------------------------------------------------------------------------
// Split-bf16 MFMA NT-GEMM: C[m][n] = sum_k A[m][k] * B[n][k]
//   A: fp32, split hi/lo on the fly during staging.
//   B: pre-split bf16 hi/lo arrays (N, K).
//   C ~= Ah*Bh + Ah*Bl + Al*Bh, fp32 MFMA accumulate (16x16x32 conventions
//   verified in this session's attn kernel).
// 128x128 tile, BK=32, 256 threads = 4 waves x (64x64).
// ---------------------------------------------------------------------------
__global__ __launch_bounds__(256) void gemm_asplit(const float* __restrict__ A,
                                                   const u16* __restrict__ Bh,
                                                   const u16* __restrict__ Bl,
                                                   float* __restrict__ C,
                                                   int M, int N, int K) {
    __shared__ u16 Ahs[128][40];   // 80B rows (proven 2-way-max pattern)
    __shared__ u16 Als[128][40];
    __shared__ u16 Bhs[128][40];
    __shared__ u16 Bls[128][40];

    const int tid = threadIdx.x;
    const int bm = blockIdx.x * 128, bn = blockIdx.y * 128;
    const int w = tid >> 6, lane = tid & 63;
    const int r16 = lane & 15, g4 = lane >> 4;
    const int wm = (w >> 1) * 64, wn = (w & 1) * 64;

    const int srow = tid >> 1;            // 0..127
    const int scol = (tid & 1) * 16;      // 16-elem half of the BK=32 chunk

    const float* pA = A + (size_t)(bm + srow) * K + scol;
    const u16* pBh = Bh + (size_t)(bn + srow) * K + scol;
    const u16* pBl = Bl + (size_t)(bn + srow) * K + scol;

    f32x4 acc[4][4];
    #pragma unroll
    for (int i = 0; i < 4; ++i)
        #pragma unroll
        for (int j = 0; j < 4; ++j)
            #pragma unroll
            for (int r = 0; r < 4; ++r) acc[i][j][r] = 0.0f;

    float4 a0, a1, a2, a3;
    uint4 b0, b1, c0, c1;      // Bh, Bl chunks
    uint4 ha, la;              // packed A hi/lo (16 elems)

    #define LOADT(k0) do {                                   \
        a0 = *(const float4*)(pA + (k0));                    \
        a1 = *(const float4*)(pA + (k0) + 4);                \
        a2 = *(const float4*)(pA + (k0) + 8);                \
        a3 = *(const float4*)(pA + (k0) + 12);               \
        b0 = *(const uint4*)(pBh + (k0));                    \
        b1 = *(const uint4*)(pBh + (k0) + 8);                \
        c0 = *(const uint4*)(pBl + (k0));                    \
        c1 = *(const uint4*)(pBl + (k0) + 8);                \
    } while (0)

    #define CONVA(ho, lo_) do {                              \
        split2(a0.x, a0.y, ho.x, lo_.x);                     \
        split2(a0.z, a0.w, ho.y, lo_.y);                     \
        split2(a1.x, a1.y, ho.z, lo_.z);                     \
        split2(a1.z, a1.w, ho.w, lo_.w);                     \
    } while (0)

    uint4 ha2, la2;
    #define CONVA2(ho, lo_) do {                             \
        split2(a2.x, a2.y, ho.x, lo_.x);                     \
        split2(a2.z, a2.w, ho.y, lo_.y);                     \
        split2(a3.x, a3.y, ho.z, lo_.z);                     \
        split2(a3.z, a3.w, ho.w, lo_.w);                     \
    } while (0)

    LOADT(0);
    CONVA(ha, la);
    CONVA2(ha2, la2);

    const int NT = K >> 5;
    for (int t = 0; t < NT; ++t) {
        __syncthreads();   // prior tile's readers done
        *(uint4*)&Ahs[srow][scol]     = ha;
        *(uint4*)&Ahs[srow][scol + 8] = ha2;
        *(uint4*)&Als[srow][scol]     = la;
        *(uint4*)&Als[srow][scol + 8] = la2;
        *(uint4*)&Bhs[srow][scol]     = b0;
        *(uint4*)&Bhs[srow][scol + 8] = b1;
        *(uint4*)&Bls[srow][scol]     = c0;
        *(uint4*)&Bls[srow][scol + 8] = c1;
        __syncthreads();   // tile staged
        if (t + 1 < NT) LOADT((t + 1) << 5);

        bf16x8s ah[4], al[4];
        #pragma unroll
        for (int i = 0; i < 4; ++i) {
            ah[i] = *(const bf16x8s*)&Ahs[wm + i * 16 + r16][8 * g4];
            al[i] = *(const bf16x8s*)&Als[wm + i * 16 + r16][8 * g4];
        }
        #pragma unroll
        for (int j = 0; j < 4; ++j) {
            const bf16x8s bh = *(const bf16x8s*)&Bhs[wn + j * 16 + r16][8 * g4];
            const bf16x8s bl = *(const bf16x8s*)&Bls[wn + j * 16 + r16][8 * g4];
            #pragma unroll
            for (int i = 0; i < 4; ++i) {
                acc[i][j] = __builtin_amdgcn_mfma_f32_16x16x32_bf16(ah[i], bh, acc[i][j], 0, 0, 0);
                acc[i][j] = __builtin_amdgcn_mfma_f32_16x16x32_bf16(ah[i], bl, acc[i][j], 0, 0, 0);
                acc[i][j] = __builtin_amdgcn_mfma_f32_16x16x32_bf16(al[i], bh, acc[i][j], 0, 0, 0);
            }
        }
        if (t + 1 < NT) { CONVA(ha, la); CONVA2(ha2, la2); }
    }

    // epilogue: D col = r16 (n), row = 4*g4 + r (m)
    #pragma unroll
    for (int i = 0; i < 4; ++i)
        #pragma unroll
        for (int j = 0; j < 4; ++j) {
            float* cp = C + (size_t)(bm + wm + i * 16 + 4 * g4) * N + (bn + wn + j * 16 + r16);
            #pragma unroll
            for (int r = 0; r < 4; ++r)
                cp[(size_t)r * N] = acc[i][j][r];
        }
    #undef LOADT
    #undef CONVA
    #undef CONVA2
}

// ---------------------------------------------------------------------------
// RoPE + head-split transpose, bf16 output.
// src: (B,S,H*128) fp32, col e = d*H + h  ->  dst: (B,H,S,128) bf16
// ---------------------------------------------------------------------------
__global__ __launch_bounds__(128) void rope_bf16(const float* __restrict__ src,
                                                 u16* __restrict__ dst,
                                                 const float2* __restrict__ tab,
                                                 int H) {
    const int s = blockIdx.x;
    const int b = blockIdx.y;
    const int tid = threadIdx.x;     // 0..127
    const int len = H * HD;

    __shared__ float row[EMB_D];

    const float* sp = src + ((size_t)b * S_LEN + s) * len;
    for (int i = tid * 4; i < len; i += 128 * 4)
        *(float4*)&row[i] = *(const float4*)(sp + i);
    __syncthreads();

    const int d = tid;
    const float2 cs = tab[s * 64 + (d & 63)];

    for (int h = 0; h < H; ++h) {
        const float xv = row[d * H + h];
        float out;
        if (d < 64)
            out = xv * cs.x - row[(d + 64) * H + h] * cs.y;
        else
            out = xv * cs.x + row[(d - 64) * H + h] * cs.y;
        dst[(((size_t)b * H + h) * S_LEN + s) * HD + d] = f2bf(out);
    }
}

// ---------------------------------------------------------------------------
// V transpose: vproj (B,S,1024) fp32 (e = d*8+kv) -> Vtg (B,8,128,S) bf16
// ---------------------------------------------------------------------------
__global__ __launch_bounds__(256) void v_transpose(const float* __restrict__ vproj,
                                                   u16* __restrict__ Vtg) {
    const int s0 = blockIdx.x * 64;
    const int kv = blockIdx.y;
    const int b  = blockIdx.z;
    const int tid = threadIdx.x;

    __shared__ u16 tile[128][72];

    {
        const int s = tid >> 2, dg = tid & 3;
        const float* src = vproj + ((size_t)(b * S_LEN) + s0 + s) * V_W + kv;
        #pragma unroll
        for (int dd = 0; dd < 32; ++dd) {
            const int d = dg * 32 + dd;
            tile[d][s] = f2bf(src[(size_t)d * 8]);
        }
    }
    __syncthreads();
    {
        const int d = tid >> 1, hf = tid & 1;
        u16* dst = Vtg + (((size_t)(b * N_KV + kv)) * HD + d) * S_LEN + s0 + hf * 32;
        #pragma unroll
        for (int u = 0; u < 4; ++u) {
            const u16* t = &tile[d][hf * 32 + u * 8];
            uint4 o;
            o.x = (u32)t[0] | ((u32)t[1] << 16);
            o.y = (u32)t[2] | ((u32)t[3] << 16);
            o.z = (u32)t[4] | ((u32)t[5] << 16);
            o.w = (u32)t[6] | ((u32)t[7] << 16);
            *(uint4*)(dst + u * 8) = o;
        }
    }
}

// ---------------------------------------------------------------------------
// MFMA flash attention (verified round 7). 16x16x32 conventions:
//   A-frag: lane holds A[row=lane&15][k = 8*(lane>>4)+j] (8 contiguous bf16)
//   B-frag: lane holds B[col=lane&15][k = 8*(lane>>4)+j] (operand stored NT)
//   D:      col = lane&15, row = 4*(lane>>4) + reg
// ---------------------------------------------------------------------------
__global__ __launch_bounds__(256) void attn_mfma16(const u16* __restrict__ Qh,
                                                   const u16* __restrict__ Kh,
                                                   const u16* __restrict__ Vtg,
                                                   float* __restrict__ Ctx) {
    __shared__ u16 Ks[32][136];     // [key][d], 272B rows
    __shared__ u16 Vt[128][40];     // [d][t], 80B rows
    __shared__ float Ss[64][36];    // [q][t] raw scores
    __shared__ u16 Pl[64][40];      // [q][t] bf16 probs
    __shared__ float mrow[64], lrow[64], resc[64];

    const int orig = blockIdx.x;                     // 1024 blocks
    const int wg = (orig & 7) * 128 + (orig >> 3);   // XCD-bijective swizzle
    const int qb = wg & 31;
    const int h  = (wg >> 5) & 15;
    const int b  = wg >> 9;
    const int kv = h >> 1;
    const int tid = threadIdx.x;
    const int w    = tid >> 6;      // wave 0..3
    const int lane = tid & 63;
    const int r16  = lane & 15;
    const int g4   = lane >> 4;     // 0..3

    const float scale = 0.022097086912079608f;   // 1/sqrt(2048)

    const u16* Kbase = Kh + ((size_t)(b * N_KV + kv)) * S_LEN * HD;
    const u16* Vbase = Vtg + ((size_t)(b * N_KV + kv)) * HD * S_LEN;

    bf16x8s qf[4];
    {
        const u16* qrow = Qh + (((size_t)(b * N_HEADS + h)) * S_LEN + qb * 64 + w * 16 + r16) * HD + 8 * g4;
        #pragma unroll
        for (int c = 0; c < 4; ++c)
            qf[c] = *(const bf16x8s*)(qrow + c * 32);
    }

    f32x4 acc[8];
    #pragma unroll
    for (int dt = 0; dt < 8; ++dt)
        #pragma unroll
        for (int r = 0; r < 4; ++r) acc[dt][r] = 0.0f;

    if (tid < 64) { mrow[tid] = -1e30f; lrow[tid] = 0.0f; }

    const int krow = tid >> 3, kslot = tid & 7;
    const int vrow = tid >> 1, vhalf = tid & 1;

    uint4 kp0, kp1, vp0, vp1;
    kp0 = kp1 = vp0 = vp1 = make_uint4(0, 0, 0, 0);

    #define LOADT(t0) do {                                                  \
        const u16* kp = Kbase + (size_t)((t0) + krow) * HD + kslot * 8;     \
        kp0 = *(const uint4*)kp;                                            \
        kp1 = *(const uint4*)(kp + 64);                                     \
        const u16* vp = Vbase + (size_t)vrow * S_LEN + (t0) + vhalf * 16;   \
        vp0 = *(const uint4*)vp;                                            \
        vp1 = *(const uint4*)(vp + 8);                                      \
    } while (0)

    LOADT(0);

    for (int t = 0; t < S_LEN / 32; ++t) {
        __syncthreads();
        *(uint4*)&Ks[krow][kslot * 8]      = kp0;
        *(uint4*)&Ks[krow][kslot * 8 + 64] = kp1;
        *(uint4*)&Vt[vrow][vhalf * 16]     = vp0;
        *(uint4*)&Vt[vrow][vhalf * 16 + 8] = vp1;
        __syncthreads();
        if (t + 1 < S_LEN / 32) LOADT((t + 1) * 32);

        // ---- QK^T ----
        f32x4 s0, s1;
        #pragma unroll
        for (int r = 0; r < 4; ++r) { s0[r] = 0.0f; s1[r] = 0.0f; }
        #pragma unroll
        for (int c = 0; c < 4; ++c) {
            bf16x8s kb0 = *(const bf16x8s*)&Ks[r16][c * 32 + 8 * g4];
            bf16x8s kb1 = *(const bf16x8s*)&Ks[16 + r16][c * 32 + 8 * g4];
            s0 = __builtin_amdgcn_mfma_f32_16x16x32_bf16(qf[c], kb0, s0, 0, 0, 0);
            s1 = __builtin_amdgcn_mfma_f32_16x16x32_bf16(qf[c], kb1, s1, 0, 0, 0);
        }
        #pragma unroll
        for (int r = 0; r < 4; ++r) {
            Ss[w * 16 + 4 * g4 + r][r16]      = s0[r];
            Ss[w * 16 + 4 * g4 + r][16 + r16] = s1[r];
        }

        // ---- softmax (4 threads per row) ----
        const int row = tid >> 2;
        const int cg  = tid & 3;
        const float4 va = *(const float4*)&Ss[row][cg * 8];
        const float4 vb = *(const float4*)&Ss[row][cg * 8 + 4];
        float mx = fmaxf(fmaxf(fmaxf(va.x, va.y), fmaxf(va.z, va.w)),
                         fmaxf(fmaxf(vb.x, vb.y), fmaxf(vb.z, vb.w)));
        mx = fmaxf(mx, __shfl_xor(mx, 1));
        mx = fmaxf(mx, __shfl_xor(mx, 2));
        const float mold = mrow[row];
        const float mnew = fmaxf(mold, mx * scale);
        const float rs = __expf(mold - mnew);
        const float p0 = __expf(fmaf(va.x, scale, -mnew));
        const float p1 = __expf(fmaf(va.y, scale, -mnew));
        const float p2 = __expf(fmaf(va.z, scale, -mnew));
        const float p3 = __expf(fmaf(va.w, scale, -mnew));
        const float p4 = __expf(fmaf(vb.x, scale, -mnew));
        const float p5 = __expf(fmaf(vb.y, scale, -mnew));
        const float p6 = __expf(fmaf(vb.z, scale, -mnew));
        const float p7 = __expf(fmaf(vb.w, scale, -mnew));
        float sum = ((p0 + p1) + (p2 + p3)) + ((p4 + p5) + (p6 + p7));
        sum += __shfl_xor(sum, 1);
        sum += __shfl_xor(sum, 2);
        if (cg == 0) {
            lrow[row] = lrow[row] * rs + sum;
            mrow[row] = mnew;
            resc[row] = rs;
        }
        {
            const u32 w0 = (u32)f2bf(p0) | ((u32)f2bf(p1) << 16);
            const u32 w1 = (u32)f2bf(p2) | ((u32)f2bf(p3) << 16);
            const u32 w2 = (u32)f2bf(p4) | ((u32)f2bf(p5) << 16);
            const u32 w3 = (u32)f2bf(p6) | ((u32)f2bf(p7) << 16);
            *(uint2*)&Pl[row][cg * 8]     = make_uint2(w0, w1);
            *(uint2*)&Pl[row][cg * 8 + 4] = make_uint2(w2, w3);
        }

        // ---- PV ----
        const float f = resc[w * 16 + r16];
        #pragma unroll
        for (int dt = 0; dt < 8; ++dt)
            #pragma unroll
            for (int r = 0; r < 4; ++r) acc[dt][r] *= f;
        const bf16x8s pb = *(const bf16x8s*)&Pl[w * 16 + r16][8 * g4];
        #pragma unroll
        for (int dt = 0; dt < 8; ++dt) {
            bf16x8s vv = *(const bf16x8s*)&Vt[16 * dt + r16][8 * g4];
            acc[dt] = __builtin_amdgcn_mfma_f32_16x16x32_bf16(vv, pb, acc[dt], 0, 0, 0);
        }
    }

    const float invl = 1.0f / lrow[w * 16 + r16];
    const size_t rowb = ((size_t)(b * S_LEN + qb * 64 + w * 16 + r16)) * EMB_D + h * HD;
    #pragma unroll
    for (int dt = 0; dt < 8; ++dt) {
        const int d = 16 * dt + 4 * g4;
        float4 o = make_float4(acc[dt][0] * invl, acc[dt][1] * invl,
                               acc[dt][2] * invl, acc[dt][3] * invl);
        *(float4*)&Ctx[rowb + d] = o;
    }
    #undef LOADT
}

// ---------------------------------------------------------------------------
extern "C" void kernel_launch(void* const* d_in, const int* in_sizes, int n_in,
                              void* d_out, int out_size, void* d_ws, size_t ws_size,
                              hipStream_t stream) {
    const float* x  = (const float*)d_in[0];   // (2,2048,2048)
    const float* Wq = (const float*)d_in[1];   // (2048,2048)
    const float* Wk = (const float*)d_in[2];   // (1024,2048)
    const float* Wv = (const float*)d_in[3];   // (1024,2048)
    const float* Wo = (const float*)d_in[4];   // (2048,2048)
    float* out = (float*)d_out;
    float* ws  = (float*)d_ws;

    // workspace layout (float offsets), 118.5 MB total:
    //  R1 (17039360 .. 25427968) holds Wq/Wk/Wv hi+lo splits during the proj
    //  GEMMs, then is overwritten by Qh/Kh/Vtg (splits dead by then).
    float2* tab  = (float2*)ws;                    //   262,144 f
    float* qproj = ws + 262144;                    // 8,388,608 f (reused as Ctx)
    float* kproj = qproj + 8388608;                // 4,194,304 f
    float* vproj = kproj + 4194304;                // 4,194,304 f

    u16* Wqh = (u16*)(ws + 17039360);              // 4,194,304 u16 (2,097,152 f)
    u16* Wql = (u16*)(ws + 19136512);
    u16* Wkh = (u16*)(ws + 21233664);              // 2,097,152 u16 (1,048,576 f)
    u16* Wkl = (u16*)(ws + 22282240);
    u16* Wvh = (u16*)(ws + 23330816);
    u16* Wvl = (u16*)(ws + 24379392);

    u16* Qh  = (u16*)(ws + 17039360);              // aliases Wqh/Wql (dead)
    u16* Kh  = (u16*)(ws + 21233664);              // aliases Wkh/Wkl (dead)
    u16* Vtg = (u16*)(ws + 23330816);              // aliases Wvh/Wvl (dead)

    u16* Woh = (u16*)(ws + 25427968);              // 2,097,152 f
    u16* Wol = (u16*)(ws + 27525120);              // end 29622272 f = 118.5 MB
    float* Ctx = qproj;

    const int M = BSZ * S_LEN;   // 4096

    trig_kernel<<<dim3(S_LEN), dim3(64), 0, stream>>>(tab);

    split_bf16<<<dim3(2048), 256, 0, stream>>>(Wq, Wqh, Wql, 524288);
    split_bf16<<<dim3(1024), 256, 0, stream>>>(Wk, Wkh, Wkl, 262144);
    split_bf16<<<dim3(1024), 256, 0, stream>>>(Wv, Wvh, Wvl, 262144);
    split_bf16<<<dim3(2048), 256, 0, stream>>>(Wo, Woh, Wol, 524288);

    gemm_asplit<<<dim3(M / 128, EMB_D / 128), 256, 0, stream>>>(x, Wqh, Wql, qproj, M, EMB_D, EMB_D);
    gemm_asplit<<<dim3(M / 128, 1024 / 128), 256, 0, stream>>>(x, Wkh, Wkl, kproj, M, 1024, EMB_D);
    gemm_asplit<<<dim3(M / 128, 1024 / 128), 256, 0, stream>>>(x, Wvh, Wvl, vproj, M, 1024, EMB_D);

    rope_bf16<<<dim3(S_LEN, BSZ), 128, 0, stream>>>(qproj, Qh, tab, N_HEADS);
    rope_bf16<<<dim3(S_LEN, BSZ), 128, 0, stream>>>(kproj, Kh, tab, N_KV);
    v_transpose<<<dim3(S_LEN / 64, N_KV, BSZ), 256, 0, stream>>>(vproj, Vtg);

    attn_mfma16<<<dim3(1024), 256, 0, stream>>>(Qh, Kh, Vtg, Ctx);

    gemm_asplit<<<dim3(M / 128, EMB_D / 128), 256, 0, stream>>>(Ctx, Woh, Wol, out, M, EMB_D, EMB_D);
}